// Round 18
// baseline (88.877 us; speedup 1.0000x reference)
//
#include <hip/hip_runtime.h>

#define MD 4
#define DD 9          // 2*MD+1
#define KK 81         // DD*DD
#define B_ 4
#define C_ 128
#define H_ 192
#define W_ 192
#define HW (H_ * W_)
#define NWG 1536      // 64 y-triples * 3 xt * 2 chh * 4 b
#define PER_XCD (NWG / 8)

// out[b,c,y,x] = (1/C) * sum_{p,o} first[b,p*9+o,y,x] * second[b,c,y+p-4,x+o-4]
//
// Round 18 = round-12 body with a y-TRIPLE (YR=3).
// Pipe model fitting r12-r17 (wall == serial sum): VALU 19.4 + DS 29.2 +
// L1 26 ~= 82us measured. Structural ratios: FMA/L1-load = 12*YR,
// FMA/ds_b128 = 4*CH. CH>4 needs 96+ window regs (spill); YR=3 fits:
// windows 48 + acc 48 + fo 4 + addr ~= 115 <= 128 ((256,2) grant, r2-proven).
// Each window row feeds up to 3 output rows (p = r, r-1, r-2 vs slabs
// 0/1/2) -> L1 term 26 -> ~17.5us. LDS 62.2KB (2 blocks/CU; occupancy
// proven irrelevant r12-r16). Stage-masked x-edge weights, same
// accumulation order as reference.
// Sentinels: VGPR 105-128, WRITE == 73728 KB exactly (else spill -> revert
// to r17), LDS ~62208, dur 68-76us.

#define FMA16(A0, A1, A2, A3, FO, O)                                   \
  A0[0] = fmaf(FO.x, w0[(O) + 0], A0[0]);                              \
  A0[1] = fmaf(FO.y, w0[(O) + 1], A0[1]);                              \
  A0[2] = fmaf(FO.z, w0[(O) + 2], A0[2]);                              \
  A0[3] = fmaf(FO.w, w0[(O) + 3], A0[3]);                              \
  A1[0] = fmaf(FO.x, w1[(O) + 0], A1[0]);                              \
  A1[1] = fmaf(FO.y, w1[(O) + 1], A1[1]);                              \
  A1[2] = fmaf(FO.z, w1[(O) + 2], A1[2]);                              \
  A1[3] = fmaf(FO.w, w1[(O) + 3], A1[3]);                              \
  A2[0] = fmaf(FO.x, w2[(O) + 0], A2[0]);                              \
  A2[1] = fmaf(FO.y, w2[(O) + 1], A2[1]);                              \
  A2[2] = fmaf(FO.z, w2[(O) + 2], A2[2]);                              \
  A2[3] = fmaf(FO.w, w2[(O) + 3], A2[3]);                              \
  A3[0] = fmaf(FO.x, w3[(O) + 0], A3[0]);                              \
  A3[1] = fmaf(FO.y, w3[(O) + 1], A3[1]);                              \
  A3[2] = fmaf(FO.z, w3[(O) + 2], A3[2]);                              \
  A3[3] = fmaf(FO.w, w3[(O) + 3], A3[3]);

__global__ __launch_bounds__(256, 2)
void corr_transpose_kernel(const float* __restrict__ first,
                           const float* __restrict__ second,
                           float* __restrict__ out) {
  __shared__ __align__(16) float ldsF[3][KK * 64];

  // bijective XCD swizzle (1536 % 8 == 0), y-triple-fastest within XCD chunk
  const int lin = blockIdx.x;
  const int wid = (lin & 7) * PER_XCD + (lin >> 3);
  const int yt  = wid % 64;
  const int t   = wid / 64;          // 0..23
  const int chh = t & 1;
  const int xt0 = ((t >> 1) % 3) * 64;
  const int b   = t / 6;
  const int y0  = yt * 3;            // output rows y0, y0+1, y0+2

  const int tid = threadIdx.x;

  // ---- stage first[b,:,y0+slab,xt0..+63] into 3 LDS slabs, edge-masked ----
  const bool edge = (xt0 != 64);     // block-uniform
#pragma unroll
  for (int slab = 0; slab < 3; ++slab) {
    const float* fbase =
        first + ((size_t)(b * KK) * H_ + (y0 + slab)) * (size_t)W_ + xt0;
    for (int idx = tid; idx < KK * 16; idx += 256) {
      const int k  = idx >> 4;
      const int xi = (idx & 15) << 2;
      float4 v = *reinterpret_cast<const float4*>(fbase + (size_t)k * HW + xi);
      if (edge) {
        const int o    = k % DD;
        const int base = xt0 + xi + o - MD;   // second-x for component 0
        if (base + 0 < 0 || base + 0 >= W_) v.x = 0.f;
        if (base + 1 < 0 || base + 1 >= W_) v.y = 0.f;
        if (base + 2 < 0 || base + 2 >= W_) v.z = 0.f;
        if (base + 3 < 0 || base + 3 >= W_) v.w = 0.f;
      }
      *reinterpret_cast<float4*>(&ldsF[slab][k * 64 + xi]) = v;
    }
  }

  const int xg = tid & 15;
  const int cg = tid >> 4;
  const int c0 = chh * 64 + cg * 4;
  const int x0 = xt0 + xg * 4;

  // clamped window offsets; OOB float4s have zeroed weights in LDS
  const bool mA = (x0 != 0);
  const bool mE = (x0 + 8 <= W_);
  const int  oa = mA ? x0 - 4 : 0;
  const int  oe = mE ? x0 + 4 : W_ - 8;

  // window rows: yy = y0-4+r, r in [r_lo, r_hi], yy within [0,191]
  const int r_lo = (y0 >= MD) ? 0 : (MD - y0);
  const int r_hi = (195 - y0 < 10) ? (195 - y0) : 10;

  const float* secB = second + (size_t)b * C_ * HW;
  const float* rp0 =
      secB + ((size_t)(c0 + 0) * H_ + (y0 - MD + r_lo)) * (size_t)W_;
  const float* rp1 = rp0 + HW;
  const float* rp2 = rp1 + HW;
  const float* rp3 = rp2 + HW;

  __syncthreads();

  float a00[4] = {0.f, 0.f, 0.f, 0.f};   // dy0, ci=0..3
  float a01[4] = {0.f, 0.f, 0.f, 0.f};
  float a02[4] = {0.f, 0.f, 0.f, 0.f};
  float a03[4] = {0.f, 0.f, 0.f, 0.f};
  float a10[4] = {0.f, 0.f, 0.f, 0.f};   // dy1
  float a11[4] = {0.f, 0.f, 0.f, 0.f};
  float a12[4] = {0.f, 0.f, 0.f, 0.f};
  float a13[4] = {0.f, 0.f, 0.f, 0.f};
  float a20[4] = {0.f, 0.f, 0.f, 0.f};   // dy2
  float a21[4] = {0.f, 0.f, 0.f, 0.f};
  float a22[4] = {0.f, 0.f, 0.f, 0.f};
  float a23[4] = {0.f, 0.f, 0.f, 0.f};

  for (int r = r_lo; r <= r_hi; ++r) {
    // windows: second[c0+ci, yy, x0-4 .. x0+7] (12 floats each)
    float w0[12], w1[12], w2[12], w3[12];
    *reinterpret_cast<float4*>(&w0[0]) = *reinterpret_cast<const float4*>(rp0 + oa);
    *reinterpret_cast<float4*>(&w0[4]) = *reinterpret_cast<const float4*>(rp0 + x0);
    *reinterpret_cast<float4*>(&w0[8]) = *reinterpret_cast<const float4*>(rp0 + oe);
    *reinterpret_cast<float4*>(&w1[0]) = *reinterpret_cast<const float4*>(rp1 + oa);
    *reinterpret_cast<float4*>(&w1[4]) = *reinterpret_cast<const float4*>(rp1 + x0);
    *reinterpret_cast<float4*>(&w1[8]) = *reinterpret_cast<const float4*>(rp1 + oe);
    *reinterpret_cast<float4*>(&w2[0]) = *reinterpret_cast<const float4*>(rp2 + oa);
    *reinterpret_cast<float4*>(&w2[4]) = *reinterpret_cast<const float4*>(rp2 + x0);
    *reinterpret_cast<float4*>(&w2[8]) = *reinterpret_cast<const float4*>(rp2 + oe);
    *reinterpret_cast<float4*>(&w3[0]) = *reinterpret_cast<const float4*>(rp3 + oa);
    *reinterpret_cast<float4*>(&w3[4]) = *reinterpret_cast<const float4*>(rp3 + x0);
    *reinterpret_cast<float4*>(&w3[8]) = *reinterpret_cast<const float4*>(rp3 + oe);

    if (r <= 8) {                       // dy=0: p = r
      const float* fbp = &ldsF[0][(r * DD) * 64 + (xg << 2)];
#pragma unroll
      for (int o = 0; o < DD; ++o) {
        const float4 fo = *reinterpret_cast<const float4*>(fbp + o * 64);
        FMA16(a00, a01, a02, a03, fo, o)
      }
    }
    if (r >= 1 && r <= 9) {             // dy=1: p = r-1
      const float* fbp = &ldsF[1][((r - 1) * DD) * 64 + (xg << 2)];
#pragma unroll
      for (int o = 0; o < DD; ++o) {
        const float4 fo = *reinterpret_cast<const float4*>(fbp + o * 64);
        FMA16(a10, a11, a12, a13, fo, o)
      }
    }
    if (r >= 2) {                       // dy=2: p = r-2
      const float* fbp = &ldsF[2][((r - 2) * DD) * 64 + (xg << 2)];
#pragma unroll
      for (int o = 0; o < DD; ++o) {
        const float4 fo = *reinterpret_cast<const float4*>(fbp + o * 64);
        FMA16(a20, a21, a22, a23, fo, o)
      }
    }

    rp0 += W_; rp1 += W_; rp2 += W_; rp3 += W_;
  }

  const float inv_c = 1.0f / (float)C_;
  float* ob0 = out + (size_t)b * C_ * HW + (size_t)y0 * W_ + x0;
  float* ob1 = ob0 + W_;
  float* ob2 = ob1 + W_;
#define STORE4(PTR, CI, ACC)                                              \
  {                                                                       \
    float4 v;                                                             \
    v.x = ACC[0] * inv_c; v.y = ACC[1] * inv_c;                           \
    v.z = ACC[2] * inv_c; v.w = ACC[3] * inv_c;                           \
    *reinterpret_cast<float4*>(PTR + (size_t)(c0 + CI) * HW) = v;         \
  }
  STORE4(ob0, 0, a00)
  STORE4(ob0, 1, a01)
  STORE4(ob0, 2, a02)
  STORE4(ob0, 3, a03)
  STORE4(ob1, 0, a10)
  STORE4(ob1, 1, a11)
  STORE4(ob1, 2, a12)
  STORE4(ob1, 3, a13)
  STORE4(ob2, 0, a20)
  STORE4(ob2, 1, a21)
  STORE4(ob2, 2, a22)
  STORE4(ob2, 3, a23)
#undef STORE4
}

extern "C" void kernel_launch(void* const* d_in, const int* in_sizes, int n_in,
                              void* d_out, int out_size, void* d_ws, size_t ws_size,
                              hipStream_t stream) {
  const float* first  = (const float*)d_in[0];
  const float* second = (const float*)d_in[1];
  float* out = (float*)d_out;

  corr_transpose_kernel<<<dim3(NWG), 256, 0, stream>>>(first, second, out);
}

// Round 19
// 84.338 us; speedup vs baseline: 1.0538x; 1.0538x over previous
//
#include <hip/hip_runtime.h>
#include <stdint.h>

#define MD 4
#define DD 9          // 2*MD+1
#define KK 81         // DD*DD
#define B_ 4
#define C_ 128
#define H_ 192
#define W_ 192
#define HW (H_ * W_)
#define NWG 2304      // 96 y-pairs * 3 xt * 2 chh * 4 b
#define PER_XCD (NWG / 8)

// out[b,c,y,x] = (1/C) * sum_{p,o} first[b,p*9+o,y,x] * second[b,c,y+p-4,x+o-4]
//
// Round 19 = byte-exact revert to round 17 (measured best: 81.8us).
// Final model (fits r12-r18 within ~2%): wall == per-wave serial sum of
// pipe times, VALU 19.4 + DS 32 + L1 29 ~= 81us.
//   - DS at algorithmic min: FMA/ds_read = 4*CH, CH=4 is register-max
//     (CH>=6 needs >=138 VGPR -> spill, r2/r13); weights read once each.
//   - L1 at practical min: FMA/load = 12*YR, YR=2 optimal (YR=3 loses to
//     occupancy + halo, r18; YR=1 is 2x worse, r4/r10).
//   - Overlap falsified 7x: software pipelines (r4-r9), stagger (r16),
//     pinned MLP (r17); double-buffered windows need ~148 VGPR (spill),
//     ch-staggered waits break fo-sharing (DS would 2-4x).
//   - HBM 52% of achievable; occupancy 20-40% changes nothing (r12-r15).
// Structure: thread = 4x*4ch*2y; y-pair window reuse; 12 volatile
// buffer_load_dwordx4 + one s_waitcnt vmcnt(0) holding all 12 as "+v";
// stage-masked x-edge weights; bijective XCD swizzle.

typedef float        f32x4 __attribute__((ext_vector_type(4)));
typedef unsigned int u32x4 __attribute__((ext_vector_type(4)));

#define FMA16(A0, A1, A2, A3, FO, O)                                   \
  A0[0] = fmaf(FO.x, w0[(O) + 0], A0[0]);                              \
  A0[1] = fmaf(FO.y, w0[(O) + 1], A0[1]);                              \
  A0[2] = fmaf(FO.z, w0[(O) + 2], A0[2]);                              \
  A0[3] = fmaf(FO.w, w0[(O) + 3], A0[3]);                              \
  A1[0] = fmaf(FO.x, w1[(O) + 0], A1[0]);                              \
  A1[1] = fmaf(FO.y, w1[(O) + 1], A1[1]);                              \
  A1[2] = fmaf(FO.z, w1[(O) + 2], A1[2]);                              \
  A1[3] = fmaf(FO.w, w1[(O) + 3], A1[3]);                              \
  A2[0] = fmaf(FO.x, w2[(O) + 0], A2[0]);                              \
  A2[1] = fmaf(FO.y, w2[(O) + 1], A2[1]);                              \
  A2[2] = fmaf(FO.z, w2[(O) + 2], A2[2]);                              \
  A2[3] = fmaf(FO.w, w2[(O) + 3], A2[3]);                              \
  A3[0] = fmaf(FO.x, w3[(O) + 0], A3[0]);                              \
  A3[1] = fmaf(FO.y, w3[(O) + 1], A3[1]);                              \
  A3[2] = fmaf(FO.z, w3[(O) + 2], A3[2]);                              \
  A3[3] = fmaf(FO.w, w3[(O) + 3], A3[3]);

#define BLD(dst, off)                                                  \
  asm volatile("buffer_load_dwordx4 %0, %1, %2, 0 offen"               \
               : "=v"(dst) : "v"(off), "s"(srsrc))

__global__ __launch_bounds__(256, 2)
void corr_transpose_kernel(const float* __restrict__ first,
                           const float* __restrict__ second,
                           float* __restrict__ out) {
  __shared__ __align__(16) float ldsF[2][KK * 64];

  // bijective XCD swizzle (2304 % 8 == 0), y-pair-fastest within an XCD chunk
  const int lin = blockIdx.x;
  const int wid = (lin & 7) * PER_XCD + (lin >> 3);
  const int yp  = wid % 96;
  const int t   = wid / 96;          // 0..23
  const int chh = t & 1;
  const int xt0 = ((t >> 1) % 3) * 64;
  const int b   = t / 6;
  const int y0  = yp * 2;            // output rows y0, y0+1

  const int tid = threadIdx.x;

  // ---- stage first[b,:,y0+slab,xt0..+63] into 2 LDS slabs, edge-masked ----
  const bool edge = (xt0 != 64);     // block-uniform
#pragma unroll
  for (int slab = 0; slab < 2; ++slab) {
    const float* fbase =
        first + ((size_t)(b * KK) * H_ + (y0 + slab)) * (size_t)W_ + xt0;
    for (int idx = tid; idx < KK * 16; idx += 256) {
      const int k  = idx >> 4;
      const int xi = (idx & 15) << 2;
      float4 v = *reinterpret_cast<const float4*>(fbase + (size_t)k * HW + xi);
      if (edge) {
        const int o    = k % DD;
        const int base = xt0 + xi + o - MD;   // second-x for component 0
        if (base + 0 < 0 || base + 0 >= W_) v.x = 0.f;
        if (base + 1 < 0 || base + 1 >= W_) v.y = 0.f;
        if (base + 2 < 0 || base + 2 >= W_) v.z = 0.f;
        if (base + 3 < 0 || base + 3 >= W_) v.w = 0.f;
      }
      *reinterpret_cast<float4*>(&ldsF[slab][k * 64 + xi]) = v;
    }
  }

  const int xg = tid & 15;
  const int cg = tid >> 4;
  const int c0 = chh * 64 + cg * 4;
  const int x0 = xt0 + xg * 4;

  // clamped window offsets; OOB float4s have zeroed weights in LDS
  const bool mA = (x0 != 0);
  const bool mE = (x0 + 8 <= W_);
  const int  oa = mA ? x0 - 4 : 0;
  const int  oe = mE ? x0 + 4 : W_ - 8;

  // row range: yy = y0-4+r, r in [r_lo, r_hi], yy within [0,191]
  const int r_lo = (y0 >= MD) ? 0 : (MD - y0);
  const int r_hi = (195 - y0 < 9) ? (195 - y0) : 9;
  const int yy0  = y0 - MD + r_lo;

  // ---- SRSRC over second[b] + 12 x 32-bit byte voffsets ----
  const uint64_t secAddr = (uint64_t)(second + (size_t)b * C_ * HW);
  u32x4 srsrc;
  srsrc.x = (unsigned int)(secAddr & 0xFFFFFFFFu);
  srsrc.y = (unsigned int)(secAddr >> 32);     // stride=0
  srsrc.z = 0xFFFFFFFFu;                       // num_records: disabled
  srsrc.w = 0x00020000u;                       // raw dword access

  unsigned int rb0 = (unsigned int)((((c0 + 0) * H_ + yy0) * W_) * 4);
  unsigned int rb1 = rb0 + HW * 4;
  unsigned int rb2 = rb1 + HW * 4;
  unsigned int rb3 = rb2 + HW * 4;
  unsigned int offA0 = rb0 + oa * 4, offM0 = rb0 + x0 * 4, offE0 = rb0 + oe * 4;
  unsigned int offA1 = rb1 + oa * 4, offM1 = rb1 + x0 * 4, offE1 = rb1 + oe * 4;
  unsigned int offA2 = rb2 + oa * 4, offM2 = rb2 + x0 * 4, offE2 = rb2 + oe * 4;
  unsigned int offA3 = rb3 + oa * 4, offM3 = rb3 + x0 * 4, offE3 = rb3 + oe * 4;

  __syncthreads();

  float a00[4] = {0.f, 0.f, 0.f, 0.f};   // dy0, ci=0..3
  float a01[4] = {0.f, 0.f, 0.f, 0.f};
  float a02[4] = {0.f, 0.f, 0.f, 0.f};
  float a03[4] = {0.f, 0.f, 0.f, 0.f};
  float a10[4] = {0.f, 0.f, 0.f, 0.f};   // dy1
  float a11[4] = {0.f, 0.f, 0.f, 0.f};
  float a12[4] = {0.f, 0.f, 0.f, 0.f};
  float a13[4] = {0.f, 0.f, 0.f, 0.f};

  for (int r = r_lo; r <= r_hi; ++r) {
    // ---- 12 loads in flight, ONE wait: pinned MLP=12 ----
    f32x4 vA0, vM0, vE0, vA1, vM1, vE1, vA2, vM2, vE2, vA3, vM3, vE3;
    BLD(vA0, offA0); BLD(vM0, offM0); BLD(vE0, offE0);
    BLD(vA1, offA1); BLD(vM1, offM1); BLD(vE1, offE1);
    BLD(vA2, offA2); BLD(vM2, offM2); BLD(vE2, offE2);
    BLD(vA3, offA3); BLD(vM3, offM3); BLD(vE3, offE3);
    asm volatile("s_waitcnt vmcnt(0)"
                 : "+v"(vA0), "+v"(vM0), "+v"(vE0),
                   "+v"(vA1), "+v"(vM1), "+v"(vE1),
                   "+v"(vA2), "+v"(vM2), "+v"(vE2),
                   "+v"(vA3), "+v"(vM3), "+v"(vE3));

    float w0[12], w1[12], w2[12], w3[12];
    *reinterpret_cast<f32x4*>(&w0[0]) = vA0;
    *reinterpret_cast<f32x4*>(&w0[4]) = vM0;
    *reinterpret_cast<f32x4*>(&w0[8]) = vE0;
    *reinterpret_cast<f32x4*>(&w1[0]) = vA1;
    *reinterpret_cast<f32x4*>(&w1[4]) = vM1;
    *reinterpret_cast<f32x4*>(&w1[8]) = vE1;
    *reinterpret_cast<f32x4*>(&w2[0]) = vA2;
    *reinterpret_cast<f32x4*>(&w2[4]) = vM2;
    *reinterpret_cast<f32x4*>(&w2[8]) = vE2;
    *reinterpret_cast<f32x4*>(&w3[0]) = vA3;
    *reinterpret_cast<f32x4*>(&w3[4]) = vM3;
    *reinterpret_cast<f32x4*>(&w3[8]) = vE3;

    if (r <= 8) {                       // dy=0 contribution, p = r
      const float* fbp = &ldsF[0][(r * DD) * 64 + (xg << 2)];
#pragma unroll
      for (int o = 0; o < DD; ++o) {
        const float4 fo = *reinterpret_cast<const float4*>(fbp + o * 64);
        FMA16(a00, a01, a02, a03, fo, o)
      }
    }
    if (r >= 1) {                       // dy=1 contribution, p = r-1
      const float* fbp = &ldsF[1][((r - 1) * DD) * 64 + (xg << 2)];
#pragma unroll
      for (int o = 0; o < DD; ++o) {
        const float4 fo = *reinterpret_cast<const float4*>(fbp + o * 64);
        FMA16(a10, a11, a12, a13, fo, o)
      }
    }

    offA0 += W_ * 4; offM0 += W_ * 4; offE0 += W_ * 4;
    offA1 += W_ * 4; offM1 += W_ * 4; offE1 += W_ * 4;
    offA2 += W_ * 4; offM2 += W_ * 4; offE2 += W_ * 4;
    offA3 += W_ * 4; offM3 += W_ * 4; offE3 += W_ * 4;
  }

  const float inv_c = 1.0f / (float)C_;
  float* ob0 = out + (size_t)b * C_ * HW + (size_t)y0 * W_ + x0;
  float* ob1 = ob0 + W_;
#define STORE4(PTR, CI, ACC)                                              \
  {                                                                       \
    float4 v;                                                             \
    v.x = ACC[0] * inv_c; v.y = ACC[1] * inv_c;                           \
    v.z = ACC[2] * inv_c; v.w = ACC[3] * inv_c;                           \
    *reinterpret_cast<float4*>(PTR + (size_t)(c0 + CI) * HW) = v;         \
  }
  STORE4(ob0, 0, a00)
  STORE4(ob0, 1, a01)
  STORE4(ob0, 2, a02)
  STORE4(ob0, 3, a03)
  STORE4(ob1, 0, a10)
  STORE4(ob1, 1, a11)
  STORE4(ob1, 2, a12)
  STORE4(ob1, 3, a13)
#undef STORE4
}

extern "C" void kernel_launch(void* const* d_in, const int* in_sizes, int n_in,
                              void* d_out, int out_size, void* d_ws, size_t ws_size,
                              hipStream_t stream) {
  const float* first  = (const float*)d_in[0];
  const float* second = (const float*)d_in[1];
  float* out = (float*)d_out;

  corr_transpose_kernel<<<dim3(NWG), 256, 0, stream>>>(first, second, out);
}

// Round 20
// 73.424 us; speedup vs baseline: 1.2105x; 1.1486x over previous
//
#include <hip/hip_runtime.h>
#include <stdint.h>

#define MD 4
#define DD 9          // 2*MD+1
#define KK 81         // DD*DD
#define B_ 4
#define C_ 128
#define H_ 192
#define W_ 192
#define HW (H_ * W_)
#define NWG 2304      // 96 y-pairs * 3 xt * 2 chh * 4 b
#define PER_XCD (NWG / 8)

// out[b,c,y,x] = (1/C) * sum_{p,o} first[b,p*9+o,y,x] * second[b,c,y+p-4,x+o-4]
//
// Round 20 = round-17/19 body (best, 81.8-84.3us) + locality-inverted work
// order. r19 counters: hbm_bytes 267 MB vs 199 MB minimum (FETCH 186 vs 123);
// at the measured ~2.5 TB/s effective BW that's ~42us of HBM service — a
// co-limiting term never attacked. Cause: old decode ran all 96 y-pairs of
// one (chh,xt,b) combo per XCD before revisiting the same second rows in the
// next combo (~170 MB later -> L3 evicted). New decode: yp = wid/24,
// combo = wid%24 -> each XCD owns 12 contiguous y-pairs x all 24 combos;
// the 24 blocks sharing a y-pair's rows run back-to-back (~4 MB/XCD working
// set, L2-resident) and adjacent y-pairs share 8/10 window rows.
// Sentinels: FETCH -> ~125-135 MB (mechanism), WRITE == 73728 KB exactly,
// VGPR 68, LDS 41472. dur 72-78us if HBM co-limits; unchanged -> declare.

typedef float        f32x4 __attribute__((ext_vector_type(4)));
typedef unsigned int u32x4 __attribute__((ext_vector_type(4)));

#define FMA16(A0, A1, A2, A3, FO, O)                                   \
  A0[0] = fmaf(FO.x, w0[(O) + 0], A0[0]);                              \
  A0[1] = fmaf(FO.y, w0[(O) + 1], A0[1]);                              \
  A0[2] = fmaf(FO.z, w0[(O) + 2], A0[2]);                              \
  A0[3] = fmaf(FO.w, w0[(O) + 3], A0[3]);                              \
  A1[0] = fmaf(FO.x, w1[(O) + 0], A1[0]);                              \
  A1[1] = fmaf(FO.y, w1[(O) + 1], A1[1]);                              \
  A1[2] = fmaf(FO.z, w1[(O) + 2], A1[2]);                              \
  A1[3] = fmaf(FO.w, w1[(O) + 3], A1[3]);                              \
  A2[0] = fmaf(FO.x, w2[(O) + 0], A2[0]);                              \
  A2[1] = fmaf(FO.y, w2[(O) + 1], A2[1]);                              \
  A2[2] = fmaf(FO.z, w2[(O) + 2], A2[2]);                              \
  A2[3] = fmaf(FO.w, w2[(O) + 3], A2[3]);                              \
  A3[0] = fmaf(FO.x, w3[(O) + 0], A3[0]);                              \
  A3[1] = fmaf(FO.y, w3[(O) + 1], A3[1]);                              \
  A3[2] = fmaf(FO.z, w3[(O) + 2], A3[2]);                              \
  A3[3] = fmaf(FO.w, w3[(O) + 3], A3[3]);

#define BLD(dst, off)                                                  \
  asm volatile("buffer_load_dwordx4 %0, %1, %2, 0 offen"               \
               : "=v"(dst) : "v"(off), "s"(srsrc))

__global__ __launch_bounds__(256, 2)
void corr_transpose_kernel(const float* __restrict__ first,
                           const float* __restrict__ second,
                           float* __restrict__ out) {
  __shared__ __align__(16) float ldsF[2][KK * 64];

  // XCD swizzle (2304 % 8 == 0) with combo-fastest order: each XCD owns 12
  // contiguous y-pairs x all 24 (chh,xt,b) combos; row reuse is immediate.
  const int lin = blockIdx.x;
  const int wid = (lin & 7) * PER_XCD + (lin >> 3);
  const int yp    = wid / 24;          // 0..95, slow-varying
  const int combo = wid % 24;          // fast-varying
  const int chh = combo & 1;
  const int xt0 = ((combo >> 1) % 3) * 64;
  const int b   = combo / 6;
  const int y0  = yp * 2;              // output rows y0, y0+1

  const int tid = threadIdx.x;

  // ---- stage first[b,:,y0+slab,xt0..+63] into 2 LDS slabs, edge-masked ----
  const bool edge = (xt0 != 64);     // block-uniform
#pragma unroll
  for (int slab = 0; slab < 2; ++slab) {
    const float* fbase =
        first + ((size_t)(b * KK) * H_ + (y0 + slab)) * (size_t)W_ + xt0;
    for (int idx = tid; idx < KK * 16; idx += 256) {
      const int k  = idx >> 4;
      const int xi = (idx & 15) << 2;
      float4 v = *reinterpret_cast<const float4*>(fbase + (size_t)k * HW + xi);
      if (edge) {
        const int o    = k % DD;
        const int base = xt0 + xi + o - MD;   // second-x for component 0
        if (base + 0 < 0 || base + 0 >= W_) v.x = 0.f;
        if (base + 1 < 0 || base + 1 >= W_) v.y = 0.f;
        if (base + 2 < 0 || base + 2 >= W_) v.z = 0.f;
        if (base + 3 < 0 || base + 3 >= W_) v.w = 0.f;
      }
      *reinterpret_cast<float4*>(&ldsF[slab][k * 64 + xi]) = v;
    }
  }

  const int xg = tid & 15;
  const int cg = tid >> 4;
  const int c0 = chh * 64 + cg * 4;
  const int x0 = xt0 + xg * 4;

  // clamped window offsets; OOB float4s have zeroed weights in LDS
  const bool mA = (x0 != 0);
  const bool mE = (x0 + 8 <= W_);
  const int  oa = mA ? x0 - 4 : 0;
  const int  oe = mE ? x0 + 4 : W_ - 8;

  // row range: yy = y0-4+r, r in [r_lo, r_hi], yy within [0,191]
  const int r_lo = (y0 >= MD) ? 0 : (MD - y0);
  const int r_hi = (195 - y0 < 9) ? (195 - y0) : 9;
  const int yy0  = y0 - MD + r_lo;

  // ---- SRSRC over second[b] + 12 x 32-bit byte voffsets ----
  const uint64_t secAddr = (uint64_t)(second + (size_t)b * C_ * HW);
  u32x4 srsrc;
  srsrc.x = (unsigned int)(secAddr & 0xFFFFFFFFu);
  srsrc.y = (unsigned int)(secAddr >> 32);     // stride=0
  srsrc.z = 0xFFFFFFFFu;                       // num_records: disabled
  srsrc.w = 0x00020000u;                       // raw dword access

  unsigned int rb0 = (unsigned int)((((c0 + 0) * H_ + yy0) * W_) * 4);
  unsigned int rb1 = rb0 + HW * 4;
  unsigned int rb2 = rb1 + HW * 4;
  unsigned int rb3 = rb2 + HW * 4;
  unsigned int offA0 = rb0 + oa * 4, offM0 = rb0 + x0 * 4, offE0 = rb0 + oe * 4;
  unsigned int offA1 = rb1 + oa * 4, offM1 = rb1 + x0 * 4, offE1 = rb1 + oe * 4;
  unsigned int offA2 = rb2 + oa * 4, offM2 = rb2 + x0 * 4, offE2 = rb2 + oe * 4;
  unsigned int offA3 = rb3 + oa * 4, offM3 = rb3 + x0 * 4, offE3 = rb3 + oe * 4;

  __syncthreads();

  float a00[4] = {0.f, 0.f, 0.f, 0.f};   // dy0, ci=0..3
  float a01[4] = {0.f, 0.f, 0.f, 0.f};
  float a02[4] = {0.f, 0.f, 0.f, 0.f};
  float a03[4] = {0.f, 0.f, 0.f, 0.f};
  float a10[4] = {0.f, 0.f, 0.f, 0.f};   // dy1
  float a11[4] = {0.f, 0.f, 0.f, 0.f};
  float a12[4] = {0.f, 0.f, 0.f, 0.f};
  float a13[4] = {0.f, 0.f, 0.f, 0.f};

  for (int r = r_lo; r <= r_hi; ++r) {
    // ---- 12 loads in flight, ONE wait: pinned MLP=12 ----
    f32x4 vA0, vM0, vE0, vA1, vM1, vE1, vA2, vM2, vE2, vA3, vM3, vE3;
    BLD(vA0, offA0); BLD(vM0, offM0); BLD(vE0, offE0);
    BLD(vA1, offA1); BLD(vM1, offM1); BLD(vE1, offE1);
    BLD(vA2, offA2); BLD(vM2, offM2); BLD(vE2, offE2);
    BLD(vA3, offA3); BLD(vM3, offM3); BLD(vE3, offE3);
    asm volatile("s_waitcnt vmcnt(0)"
                 : "+v"(vA0), "+v"(vM0), "+v"(vE0),
                   "+v"(vA1), "+v"(vM1), "+v"(vE1),
                   "+v"(vA2), "+v"(vM2), "+v"(vE2),
                   "+v"(vA3), "+v"(vM3), "+v"(vE3));

    float w0[12], w1[12], w2[12], w3[12];
    *reinterpret_cast<f32x4*>(&w0[0]) = vA0;
    *reinterpret_cast<f32x4*>(&w0[4]) = vM0;
    *reinterpret_cast<f32x4*>(&w0[8]) = vE0;
    *reinterpret_cast<f32x4*>(&w1[0]) = vA1;
    *reinterpret_cast<f32x4*>(&w1[4]) = vM1;
    *reinterpret_cast<f32x4*>(&w1[8]) = vE1;
    *reinterpret_cast<f32x4*>(&w2[0]) = vA2;
    *reinterpret_cast<f32x4*>(&w2[4]) = vM2;
    *reinterpret_cast<f32x4*>(&w2[8]) = vE2;
    *reinterpret_cast<f32x4*>(&w3[0]) = vA3;
    *reinterpret_cast<f32x4*>(&w3[4]) = vM3;
    *reinterpret_cast<f32x4*>(&w3[8]) = vE3;

    if (r <= 8) {                       // dy=0 contribution, p = r
      const float* fbp = &ldsF[0][(r * DD) * 64 + (xg << 2)];
#pragma unroll
      for (int o = 0; o < DD; ++o) {
        const float4 fo = *reinterpret_cast<const float4*>(fbp + o * 64);
        FMA16(a00, a01, a02, a03, fo, o)
      }
    }
    if (r >= 1) {                       // dy=1 contribution, p = r-1
      const float* fbp = &ldsF[1][((r - 1) * DD) * 64 + (xg << 2)];
#pragma unroll
      for (int o = 0; o < DD; ++o) {
        const float4 fo = *reinterpret_cast<const float4*>(fbp + o * 64);
        FMA16(a10, a11, a12, a13, fo, o)
      }
    }

    offA0 += W_ * 4; offM0 += W_ * 4; offE0 += W_ * 4;
    offA1 += W_ * 4; offM1 += W_ * 4; offE1 += W_ * 4;
    offA2 += W_ * 4; offM2 += W_ * 4; offE2 += W_ * 4;
    offA3 += W_ * 4; offM3 += W_ * 4; offE3 += W_ * 4;
  }

  const float inv_c = 1.0f / (float)C_;
  float* ob0 = out + (size_t)b * C_ * HW + (size_t)y0 * W_ + x0;
  float* ob1 = ob0 + W_;
#define STORE4(PTR, CI, ACC)                                              \
  {                                                                       \
    float4 v;                                                             \
    v.x = ACC[0] * inv_c; v.y = ACC[1] * inv_c;                           \
    v.z = ACC[2] * inv_c; v.w = ACC[3] * inv_c;                           \
    *reinterpret_cast<float4*>(PTR + (size_t)(c0 + CI) * HW) = v;         \
  }
  STORE4(ob0, 0, a00)
  STORE4(ob0, 1, a01)
  STORE4(ob0, 2, a02)
  STORE4(ob0, 3, a03)
  STORE4(ob1, 0, a10)
  STORE4(ob1, 1, a11)
  STORE4(ob1, 2, a12)
  STORE4(ob1, 3, a13)
#undef STORE4
}

extern "C" void kernel_launch(void* const* d_in, const int* in_sizes, int n_in,
                              void* d_out, int out_size, void* d_ws, size_t ws_size,
                              hipStream_t stream) {
  const float* first  = (const float*)d_in[0];
  const float* second = (const float*)d_in[1];
  float* out = (float*)d_out;

  corr_transpose_kernel<<<dim3(NWG), 256, 0, stream>>>(first, second, out);
}